// Round 6
// baseline (349.170 us; speedup 1.0000x reference)
//
#include <hip/hip_runtime.h>
#include <math.h>

#define NNODES 20000
#define NEDGES 320000
#define RREL 8
#define EPSBN 1e-5f

typedef float f32x4 __attribute__((ext_vector_type(4)));
typedef __bf16 bf16x8 __attribute__((ext_vector_type(8)));
typedef unsigned short u16x8 __attribute__((ext_vector_type(8)));

static __device__ __forceinline__ unsigned short f2bf(float f) {
    unsigned int x = __builtin_bit_cast(unsigned int, f);
    unsigned int r = x + 0x7FFFu + ((x >> 16) & 1u);
    return (unsigned short)(r >> 16);
}
static __device__ __forceinline__ float bf2f(unsigned short u) {
    unsigned int x = ((unsigned int)u) << 16;
    return __builtin_bit_cast(float, x);
}

// ---------------- CSR build ----------------
__global__ __launch_bounds__(256) void k_count(const int* __restrict__ dst, const int* __restrict__ et,
                                               int* __restrict__ cnt) {
    int e = blockIdx.x * 256 + threadIdx.x;
    if (e >= NEDGES) return;
    atomicAdd(&cnt[dst[e] * RREL + et[e]], 1);
}

__global__ __launch_bounds__(256) void k_invdeg(const int* __restrict__ cnt, float* __restrict__ inv,
                                                int* __restrict__ deg) {
    int i = blockIdx.x * 256 + threadIdx.x;
    if (i >= NNODES) return;
    const int4* p = (const int4*)(cnt + i * 8);
    int4 a = p[0], b = p[1];
    deg[i] = a.x + a.y + a.z + a.w + b.x + b.y + b.z + b.w;
    float4 i0, i1;
    i0.x = 1.0f / (float)(a.x > 0 ? a.x : 1);
    i0.y = 1.0f / (float)(a.y > 0 ? a.y : 1);
    i0.z = 1.0f / (float)(a.z > 0 ? a.z : 1);
    i0.w = 1.0f / (float)(a.w > 0 ? a.w : 1);
    i1.x = 1.0f / (float)(b.x > 0 ? b.x : 1);
    i1.y = 1.0f / (float)(b.y > 0 ? b.y : 1);
    i1.z = 1.0f / (float)(b.z > 0 ? b.z : 1);
    i1.w = 1.0f / (float)(b.w > 0 ? b.w : 1);
    ((float4*)(inv + i * 8))[0] = i0;
    ((float4*)(inv + i * 8))[1] = i1;
}

__global__ __launch_bounds__(256) void k_scan(const int* __restrict__ deg, int* __restrict__ start,
                                              int* __restrict__ cursor) {
    __shared__ int part[256];
    int t = threadIdx.x;
    const int chunk = (NNODES + 255) / 256;
    int i0 = t * chunk, i1 = i0 + chunk;
    if (i1 > NNODES) i1 = NNODES;
    int s = 0;
    for (int i = i0; i < i1; i++) s += deg[i];
    part[t] = s;
    __syncthreads();
    if (t == 0) {
        int acc = 0;
        for (int j = 0; j < 256; j++) { int v = part[j]; part[j] = acc; acc += v; }
    }
    __syncthreads();
    int acc = part[t];
    for (int i = i0; i < i1; i++) { start[i] = acc; cursor[i] = acc; acc += deg[i]; }
}

__global__ __launch_bounds__(256) void k_fill(const int* __restrict__ src, const int* __restrict__ dst,
                                              const int* __restrict__ et, int* __restrict__ cursor,
                                              int* __restrict__ csr) {
    int e = blockIdx.x * 256 + threadIdx.x;
    if (e >= NEDGES) return;
    int pos = atomicAdd(&cursor[dst[e]], 1);
    csr[pos] = src[e] * 8 + et[e];
}

// ---------------- fused prep ----------------
#define PR0 (NNODES * 32)
#define PR1 (2048 * 256)
#define PR2 (256 * 256)
#define PR3 (1024 * 256)
__global__ __launch_bounds__(256) void k_prep(const float* __restrict__ x, const float* __restrict__ Wrel,
                                              const float* __restrict__ Wroot,
                                              const float* __restrict__ Wq, const float* __restrict__ Wk,
                                              const float* __restrict__ Wv, const float* __restrict__ Ws,
                                              const float* __restrict__ bq, const float* __restrict__ bk,
                                              const float* __restrict__ bv, const float* __restrict__ bs,
                                              unsigned short* __restrict__ xb, unsigned short* __restrict__ Brel,
                                              unsigned short* __restrict__ Broot, unsigned short* __restrict__ B2t,
                                              float* __restrict__ bias2) {
    int i = blockIdx.x * 256 + threadIdx.x;
    if (i < PR0) {
        const float4* p = (const float4*)(x + (size_t)i * 8);
        float4 v0 = p[0], v1 = p[1];
        u16x8 w;
        w[0] = f2bf(v0.x); w[1] = f2bf(v0.y); w[2] = f2bf(v0.z); w[3] = f2bf(v0.w);
        w[4] = f2bf(v1.x); w[5] = f2bf(v1.y); w[6] = f2bf(v1.z); w[7] = f2bf(v1.w);
        *(u16x8*)(xb + (size_t)i * 8) = w;
    } else if (i < PR0 + PR1) {
        int idx = i - PR0;
        int col = idx >> 8, g = idx & 255;
        int r = col >> 8, h = col & 255;
        Brel[idx] = f2bf(Wrel[(size_t)r * 65536 + (size_t)g * 256 + h]);
    } else if (i < PR0 + PR1 + PR2) {
        int idx = i - PR0 - PR1;
        int h = idx >> 8, g = idx & 255;
        Broot[idx] = f2bf(Wroot[(size_t)g * 256 + h]);
    } else {
        int idx = i - PR0 - PR1 - PR2;
        int c = idx >> 8, g = idx & 255;
        const float* W = (c < 256) ? Wq : (c < 512) ? Wk : (c < 768) ? Wv : Ws;
        int cc = c & 255;
        B2t[idx] = f2bf(W[(size_t)g * 256 + cc]);
        if (g == 0) {
            const float* B = (c < 256) ? bq : (c < 512) ? bk : (c < 768) ? bv : bs;
            bias2[c] = B[cc];
        }
    }
}

// ---------------- bf16 MFMA GEMM v3 ----------------
// A[M,256] bf16, resident in LDS (fetched once per block, XOR-swizzled).
// Bt[Ncols,256] bf16 pre-transposed. Block: 64 rows x cpb cols (BN=128 tiles).
// BK=64, double-buffered Bs with async reg-staging, ONE barrier per k-iter.
// Swizzle: 16B-chunk index c stored at c ^ (row&7)  [T2; bank-verified uniform]
// MODE 1: bf16 out = acc + bias + addin(f32); MODE 2: bf16 out = acc;
// MODE 3: col<768 -> bf16 C; col>=768 -> f32 C2; + bias
template<int MODE>
__global__ __launch_bounds__(256) void k_gemm3(const unsigned short* __restrict__ A,
                                               const unsigned short* __restrict__ Bt,
                                               const float* __restrict__ bias, const float* __restrict__ addin,
                                               void* __restrict__ Cv, float* __restrict__ C2,
                                               int M, int Ncols, int cpb) {
    __shared__ __align__(16) unsigned short As[64 * 256];      // 32 KB
    __shared__ __align__(16) unsigned short Bs[2][128 * 64];   // 2 x 16 KB
    int tid = threadIdx.x;
    int lane = tid & 63, wid = tid >> 6;
    int wr = wid >> 1, wc = wid & 1;
    int lr = lane & 15, lq = lane >> 4;
    int brow = blockIdx.x * 64;
    int colBeg = blockIdx.y * cpb;

    // ---- stage A (64 x 256) once, swizzled; coalesced 64B per 4-lane group ----
    {
        int row = tid >> 2;
        int a4 = tid & 3;
        int grow = brow + row;
        const unsigned short* gp = A + (size_t)grow * 256 + a4 * 8;
        unsigned short* lp = As + row * 256;
        int r7 = row & 7;
        #pragma unroll
        for (int j = 0; j < 8; j++) {
            u16x8 v = {0, 0, 0, 0, 0, 0, 0, 0};
            if (grow < M) v = *(const u16x8*)(gp + j * 32);
            int chunk = a4 + j * 4;
            *(u16x8*)(lp + ((chunk ^ r7) << 3)) = v;
        }
    }

    int nIter = (cpb >> 7) << 2;     // col-tiles * 4
    int srow = tid >> 1;             // 0..127
    int sseg = tid & 1;
    int sr7 = srow & 7;
    u16x8 Rb0, Rb1, Rb2, Rb3;

    // preload iter 0
    {
        const unsigned short* gp = Bt + (size_t)(colBeg + srow) * 256 + sseg * 32;
        Rb0 = *(const u16x8*)(gp);
        Rb1 = *(const u16x8*)(gp + 8);
        Rb2 = *(const u16x8*)(gp + 16);
        Rb3 = *(const u16x8*)(gp + 24);
    }
    {
        unsigned short* lp = Bs[0] + srow * 64;
        *(u16x8*)(lp + (((sseg * 4 + 0) ^ sr7) << 3)) = Rb0;
        *(u16x8*)(lp + (((sseg * 4 + 1) ^ sr7) << 3)) = Rb1;
        *(u16x8*)(lp + (((sseg * 4 + 2) ^ sr7) << 3)) = Rb2;
        *(u16x8*)(lp + (((sseg * 4 + 3) ^ sr7) << 3)) = Rb3;
    }
    int cur = 0;

    f32x4 acc[2][4];
    for (int it = 0; it < nIter; ++it) {
        int ct = it >> 2, kt = it & 3;
        int bcol = colBeg + (ct << 7);
        if (kt == 0) {
            #pragma unroll
            for (int i = 0; i < 2; i++)
                #pragma unroll
                for (int j = 0; j < 4; j++) acc[i][j] = (f32x4){0.f, 0.f, 0.f, 0.f};
        }
        // issue next tile's B loads (in flight across the barrier and MFMA)
        if (it + 1 < nIter) {
            int nct = (it + 1) >> 2, nkt = (it + 1) & 3;
            const unsigned short* gp = Bt + (size_t)(colBeg + (nct << 7) + srow) * 256 + nkt * 64 + sseg * 32;
            Rb0 = *(const u16x8*)(gp);
            Rb1 = *(const u16x8*)(gp + 8);
            Rb2 = *(const u16x8*)(gp + 16);
            Rb3 = *(const u16x8*)(gp + 24);
        }
        __syncthreads();   // Bs[cur] visible; all prior reads of Bs[cur^1] complete

        // 16 MFMA on As + Bs[cur]
        int r7a = lr & 7;
        const unsigned short* arow0 = As + (wr * 32 + lr) * 256;
        const unsigned short* arow1 = arow0 + 16 * 256;
        const unsigned short* bbase = Bs[cur] + (wc * 64 + lr) * 64;
        #pragma unroll
        for (int s = 0; s < 2; s++) {
            int aoff = ((kt * 8 + s * 4 + lq) ^ r7a) << 3;
            int boff = ((s * 4 + lq) ^ r7a) << 3;
            bf16x8 a0 = *(const bf16x8*)(arow0 + aoff);
            bf16x8 a1 = *(const bf16x8*)(arow1 + aoff);
            bf16x8 b0 = *(const bf16x8*)(bbase + boff);
            bf16x8 b1 = *(const bf16x8*)(bbase + 16 * 64 + boff);
            bf16x8 b2 = *(const bf16x8*)(bbase + 32 * 64 + boff);
            bf16x8 b3 = *(const bf16x8*)(bbase + 48 * 64 + boff);
            acc[0][0] = __builtin_amdgcn_mfma_f32_16x16x32_bf16(a0, b0, acc[0][0], 0, 0, 0);
            acc[0][1] = __builtin_amdgcn_mfma_f32_16x16x32_bf16(a0, b1, acc[0][1], 0, 0, 0);
            acc[0][2] = __builtin_amdgcn_mfma_f32_16x16x32_bf16(a0, b2, acc[0][2], 0, 0, 0);
            acc[0][3] = __builtin_amdgcn_mfma_f32_16x16x32_bf16(a0, b3, acc[0][3], 0, 0, 0);
            acc[1][0] = __builtin_amdgcn_mfma_f32_16x16x32_bf16(a1, b0, acc[1][0], 0, 0, 0);
            acc[1][1] = __builtin_amdgcn_mfma_f32_16x16x32_bf16(a1, b1, acc[1][1], 0, 0, 0);
            acc[1][2] = __builtin_amdgcn_mfma_f32_16x16x32_bf16(a1, b2, acc[1][2], 0, 0, 0);
            acc[1][3] = __builtin_amdgcn_mfma_f32_16x16x32_bf16(a1, b3, acc[1][3], 0, 0, 0);
        }

        // write next tile's B into the other buffer (visible after next barrier)
        if (it + 1 < nIter) {
            unsigned short* lp = Bs[cur ^ 1] + srow * 64;
            *(u16x8*)(lp + (((sseg * 4 + 0) ^ sr7) << 3)) = Rb0;
            *(u16x8*)(lp + (((sseg * 4 + 1) ^ sr7) << 3)) = Rb1;
            *(u16x8*)(lp + (((sseg * 4 + 2) ^ sr7) << 3)) = Rb2;
            *(u16x8*)(lp + (((sseg * 4 + 3) ^ sr7) << 3)) = Rb3;
        }
        cur ^= 1;

        if (kt == 3) {
            // epilogue: C/D layout col=lane&15, row=(lane>>4)*4+reg
            #pragma unroll
            for (int rm = 0; rm < 2; rm++) {
                #pragma unroll
                for (int cn = 0; cn < 4; cn++) {
                    int row = brow + wr * 32 + rm * 16 + lq * 4;
                    int col = bcol + wc * 64 + cn * 16 + lr;
                    #pragma unroll
                    for (int r = 0; r < 4; r++) {
                        int gr = row + r;
                        if (gr >= M) continue;
                        float v = acc[rm][cn][r];
                        if (MODE == 2) {
                            ((unsigned short*)Cv)[(size_t)gr * Ncols + col] = f2bf(v);
                        } else if (MODE == 1) {
                            v += bias[col] + addin[(size_t)gr * 256 + col];
                            ((unsigned short*)Cv)[(size_t)gr * 256 + col] = f2bf(v);
                        } else {
                            v += bias[col];
                            if (col < 768) ((unsigned short*)Cv)[(size_t)gr * 768 + col] = f2bf(v);
                            else           C2[(size_t)gr * 256 + (col - 768)] = v;
                        }
                    }
                }
            }
        }
    }
}

// ---------------- RGCN aggregate: gather, one wave per dst node, edges batched x4 ----------------
__global__ __launch_bounds__(256) void k_rgcn(const unsigned short* __restrict__ Yall, const int* __restrict__ csr,
                                              const int* __restrict__ start, const int* __restrict__ deg,
                                              const float* __restrict__ inv, float* __restrict__ agg) {
    int node = blockIdx.x * 4 + (threadIdx.x >> 6);
    int lane = threadIdx.x & 63;
    if (node >= NNODES) return;
    int s0 = start[node], n = deg[node];
    float4 acc = make_float4(0.f, 0.f, 0.f, 0.f);
    int j = 0;
    for (; j + 4 <= n; j += 4) {
        int p0 = csr[s0 + j], p1 = csr[s0 + j + 1], p2 = csr[s0 + j + 2], p3 = csr[s0 + j + 3];
        float c0 = inv[node * RREL + (p0 & 7)];
        float c1 = inv[node * RREL + (p1 & 7)];
        float c2 = inv[node * RREL + (p2 & 7)];
        float c3 = inv[node * RREL + (p3 & 7)];
        ushort4 y0 = *(const ushort4*)(Yall + (size_t)(p0 >> 3) * 2048 + (p0 & 7) * 256 + lane * 4);
        ushort4 y1 = *(const ushort4*)(Yall + (size_t)(p1 >> 3) * 2048 + (p1 & 7) * 256 + lane * 4);
        ushort4 y2 = *(const ushort4*)(Yall + (size_t)(p2 >> 3) * 2048 + (p2 & 7) * 256 + lane * 4);
        ushort4 y3 = *(const ushort4*)(Yall + (size_t)(p3 >> 3) * 2048 + (p3 & 7) * 256 + lane * 4);
        acc.x += c0 * bf2f(y0.x) + c1 * bf2f(y1.x) + c2 * bf2f(y2.x) + c3 * bf2f(y3.x);
        acc.y += c0 * bf2f(y0.y) + c1 * bf2f(y1.y) + c2 * bf2f(y2.y) + c3 * bf2f(y3.y);
        acc.z += c0 * bf2f(y0.z) + c1 * bf2f(y1.z) + c2 * bf2f(y2.z) + c3 * bf2f(y3.z);
        acc.w += c0 * bf2f(y0.w) + c1 * bf2f(y1.w) + c2 * bf2f(y2.w) + c3 * bf2f(y3.w);
    }
    for (; j < n; j++) {
        int pk = csr[s0 + j];
        float sc = inv[node * RREL + (pk & 7)];
        ushort4 y = *(const ushort4*)(Yall + (size_t)(pk >> 3) * 2048 + (pk & 7) * 256 + lane * 4);
        acc.x += sc * bf2f(y.x);
        acc.y += sc * bf2f(y.y);
        acc.z += sc * bf2f(y.z);
        acc.w += sc * bf2f(y.w);
    }
    ((float4*)(agg + (size_t)node * 256))[lane] = acc;
}

// ---------------- fused attention: one wave per node, online softmax, edges batched x4 ----------------
__global__ __launch_bounds__(256) void k_attn(const unsigned short* __restrict__ QKV, const int* __restrict__ csr,
                                              const int* __restrict__ start, const int* __restrict__ deg,
                                              float* __restrict__ out) {
    int node = blockIdx.x * 4 + (threadIdx.x >> 6);
    int lane = threadIdx.x & 63;
    if (node >= NNODES) return;
    int s0 = start[node], n = deg[node];
    if (n == 0) return;
    ushort4 qu = *(const ushort4*)(QKV + (size_t)node * 768 + lane * 4);
    float q0 = bf2f(qu.x), q1 = bf2f(qu.y), q2 = bf2f(qu.z), q3 = bf2f(qu.w);
    float m = -INFINITY, den = 0.f;
    float4 acc = make_float4(0.f, 0.f, 0.f, 0.f);
    int j = 0;
    for (; j + 4 <= n; j += 4) {
        const unsigned short* b0 = QKV + (size_t)(csr[s0 + j] >> 3) * 768;
        const unsigned short* b1 = QKV + (size_t)(csr[s0 + j + 1] >> 3) * 768;
        const unsigned short* b2 = QKV + (size_t)(csr[s0 + j + 2] >> 3) * 768;
        const unsigned short* b3 = QKV + (size_t)(csr[s0 + j + 3] >> 3) * 768;
        ushort4 k0 = *(const ushort4*)(b0 + 256 + lane * 4);
        ushort4 k1 = *(const ushort4*)(b1 + 256 + lane * 4);
        ushort4 k2 = *(const ushort4*)(b2 + 256 + lane * 4);
        ushort4 k3 = *(const ushort4*)(b3 + 256 + lane * 4);
        ushort4 v0 = *(const ushort4*)(b0 + 512 + lane * 4);
        ushort4 v1 = *(const ushort4*)(b1 + 512 + lane * 4);
        ushort4 v2 = *(const ushort4*)(b2 + 512 + lane * 4);
        ushort4 v3 = *(const ushort4*)(b3 + 512 + lane * 4);
        float p0 = q0 * bf2f(k0.x) + q1 * bf2f(k0.y) + q2 * bf2f(k0.z) + q3 * bf2f(k0.w);
        float p1 = q0 * bf2f(k1.x) + q1 * bf2f(k1.y) + q2 * bf2f(k1.z) + q3 * bf2f(k1.w);
        float p2 = q0 * bf2f(k2.x) + q1 * bf2f(k2.y) + q2 * bf2f(k2.z) + q3 * bf2f(k2.w);
        float p3 = q0 * bf2f(k3.x) + q1 * bf2f(k3.y) + q2 * bf2f(k3.z) + q3 * bf2f(k3.w);
        #pragma unroll
        for (int o = 32; o; o >>= 1) {
            p0 += __shfl_xor(p0, o);
            p1 += __shfl_xor(p1, o);
            p2 += __shfl_xor(p2, o);
            p3 += __shfl_xor(p3, o);
        }
        p0 *= 0.0625f; p1 *= 0.0625f; p2 *= 0.0625f; p3 *= 0.0625f;
        float pm = fmaxf(fmaxf(p0, p1), fmaxf(p2, p3));
        if (pm > m) {
            float rr = __expf(m - pm);
            den *= rr;
            acc.x *= rr; acc.y *= rr; acc.z *= rr; acc.w *= rr;
            m = pm;
        }
        float e0 = __expf(p0 - m), e1 = __expf(p1 - m), e2 = __expf(p2 - m), e3 = __expf(p3 - m);
        den += e0 + e1 + e2 + e3;
        acc.x += e0 * bf2f(v0.x) + e1 * bf2f(v1.x) + e2 * bf2f(v2.x) + e3 * bf2f(v3.x);
        acc.y += e0 * bf2f(v0.y) + e1 * bf2f(v1.y) + e2 * bf2f(v2.y) + e3 * bf2f(v3.y);
        acc.z += e0 * bf2f(v0.z) + e1 * bf2f(v1.z) + e2 * bf2f(v2.z) + e3 * bf2f(v3.z);
        acc.w += e0 * bf2f(v0.w) + e1 * bf2f(v1.w) + e2 * bf2f(v2.w) + e3 * bf2f(v3.w);
    }
    for (; j < n; j++) {
        const unsigned short* base = QKV + (size_t)(csr[s0 + j] >> 3) * 768;
        ushort4 ku = *(const ushort4*)(base + 256 + lane * 4);
        ushort4 vu = *(const ushort4*)(base + 512 + lane * 4);
        float p = q0 * bf2f(ku.x) + q1 * bf2f(ku.y) + q2 * bf2f(ku.z) + q3 * bf2f(ku.w);
        #pragma unroll
        for (int o = 32; o; o >>= 1) p += __shfl_xor(p, o);
        p *= 0.0625f;
        if (p > m) {
            float rr = __expf(m - p);
            den *= rr;
            acc.x *= rr; acc.y *= rr; acc.z *= rr; acc.w *= rr;
            m = p;
        }
        float ex = __expf(p - m);
        den += ex;
        acc.x += ex * bf2f(vu.x); acc.y += ex * bf2f(vu.y);
        acc.z += ex * bf2f(vu.z); acc.w += ex * bf2f(vu.w);
    }
    float rinv = 1.0f / fmaxf(den, 1e-16f);
    float4* o4 = (float4*)(out + (size_t)node * 256);
    float4 o = o4[lane];
    o.x += acc.x * rinv; o.y += acc.y * rinv; o.z += acc.z * rinv; o.w += acc.w * rinv;
    o4[lane] = o;
}

// ---------------- batch norm + leaky relu ----------------
__global__ __launch_bounds__(256) void k_bnstats(const float* __restrict__ out, float* __restrict__ sums,
                                                 float* __restrict__ sumsq) {
    int c = threadIdx.x;
    int rows_per = (NNODES + gridDim.x - 1) / gridDim.x;
    int r0 = blockIdx.x * rows_per;
    int r1 = r0 + rows_per; if (r1 > NNODES) r1 = NNODES;
    float s = 0.f, ss = 0.f;
    for (int r = r0; r < r1; r++) {
        float v = out[(size_t)r * 256 + c];
        s += v; ss += v * v;
    }
    atomicAdd(&sums[c], s);
    atomicAdd(&sumsq[c], ss);
}

__global__ __launch_bounds__(256) void k_bnapply(float4* __restrict__ out, const float* __restrict__ sums,
                                                 const float* __restrict__ sumsq, const float* __restrict__ gamma,
                                                 const float* __restrict__ beta) {
    int i = blockIdx.x * 256 + threadIdx.x;
    if (i >= NNODES * 64) return;
    int c4 = i & 63;
    float4 sc, sh;
    #pragma unroll
    for (int t = 0; t < 4; t++) {
        int c = c4 * 4 + t;
        float mu = sums[c] * (1.0f / NNODES);
        float var = sumsq[c] * (1.0f / NNODES) - mu * mu;
        float s = gamma[c] * rsqrtf(fmaxf(var, 0.f) + EPSBN);
        ((float*)&sc)[t] = s;
        ((float*)&sh)[t] = beta[c] - mu * s;
    }
    float4 v = out[i];
    v.x = v.x * sc.x + sh.x; v.y = v.y * sc.y + sh.y;
    v.z = v.z * sc.z + sh.z; v.w = v.w * sc.w + sh.w;
    v.x = v.x > 0.f ? v.x : 0.01f * v.x;
    v.y = v.y > 0.f ? v.y : 0.01f * v.y;
    v.z = v.z > 0.f ? v.z : 0.01f * v.z;
    v.w = v.w > 0.f ? v.w : 0.01f * v.w;
    out[i] = v;
}

extern "C" void kernel_launch(void* const* d_in, const int* in_sizes, int n_in,
                              void* d_out, int out_size, void* d_ws, size_t ws_size,
                              hipStream_t stream) {
    const float* x = (const float*)d_in[0];
    const int* ei = (const int*)d_in[1];
    const int* etype = (const int*)d_in[2];
    const float* Wrel = (const float*)d_in[3];
    const float* Wroot = (const float*)d_in[4];
    const float* b1 = (const float*)d_in[5];
    const float* Wq = (const float*)d_in[6];
    const float* bq = (const float*)d_in[7];
    const float* Wk = (const float*)d_in[8];
    const float* bk = (const float*)d_in[9];
    const float* Wv = (const float*)d_in[10];
    const float* bv = (const float*)d_in[11];
    const float* Ws = (const float*)d_in[12];
    const float* bs = (const float*)d_in[13];
    const float* gamma = (const float*)d_in[14];
    const float* beta = (const float*)d_in[15];
    float* out = (float*)d_out;

    const int* srcA = ei;
    const int* dstA = ei + NEDGES;

    char* w = (char*)d_ws;
    unsigned short* Yall = (unsigned short*)w;  w += (size_t)NNODES * 2048 * 2;
    unsigned short* x_bf = (unsigned short*)w;  w += (size_t)NNODES * 256 * 2;
    unsigned short* x1bf = (unsigned short*)w;  w += (size_t)NNODES * 256 * 2;
    float* agg = (float*)w;                     w += (size_t)NNODES * 256 * 4;
    unsigned short* QKVbf = (unsigned short*)w; w += (size_t)NNODES * 768 * 2;
    unsigned short* Brel = (unsigned short*)w;  w += (size_t)2048 * 256 * 2;
    unsigned short* Broot = (unsigned short*)w; w += (size_t)256 * 256 * 2;
    unsigned short* B2t = (unsigned short*)w;   w += (size_t)1024 * 256 * 2;
    float* bias2 = (float*)w;                   w += 1024 * 4;
    int* cnt = (int*)w;                         w += (size_t)NNODES * RREL * 4;
    float* invc = (float*)w;                    w += (size_t)NNODES * RREL * 4;
    int* deg = (int*)w;                         w += (size_t)NNODES * 4;
    int* startv = (int*)w;                      w += (size_t)NNODES * 4;
    int* cursor = (int*)w;                      w += (size_t)NNODES * 4;
    int* csr = (int*)w;                         w += (size_t)NEDGES * 4;
    float* sums = (float*)w;                    w += 1024;
    float* sumsq = (float*)w;                   w += 1024;
    size_t need = (size_t)(w - (char*)d_ws);
    if (ws_size < need) return;

    hipMemsetAsync(cnt, 0, (size_t)NNODES * RREL * 4, stream);
    hipMemsetAsync(sums, 0, 2048, stream);

    k_count<<<(NEDGES + 255) / 256, 256, 0, stream>>>(dstA, etype, cnt);
    k_invdeg<<<(NNODES + 255) / 256, 256, 0, stream>>>(cnt, invc, deg);
    k_scan<<<1, 256, 0, stream>>>(deg, startv, cursor);
    k_fill<<<(NEDGES + 255) / 256, 256, 0, stream>>>(srcA, dstA, etype, cursor, csr);

    k_prep<<<(PR0 + PR1 + PR2 + PR3) / 256, 256, 0, stream>>>(x, Wrel, Wroot, Wq, Wk, Wv, Ws,
                                                              bq, bk, bv, bs, x_bf, Brel, Broot, B2t, bias2);

    // Yall[N,2048] bf16 = x @ [W_0|...|W_7]
    k_gemm3<2><<<dim3(313, 4), 256, 0, stream>>>(x_bf, Brel, nullptr, nullptr, (void*)Yall, nullptr,
                                                 NNODES, 2048, 512);

    // agg[dst] = sum_r inv * Yall[src, r]
    k_rgcn<<<(NNODES + 3) / 4, 256, 0, stream>>>(Yall, csr, startv, deg, invc, agg);

    // x1_bf = bf16(x @ W_root + b1 + agg)
    k_gemm3<1><<<dim3(313, 2), 256, 0, stream>>>(x_bf, Broot, b1, agg, (void*)x1bf, nullptr,
                                                 NNODES, 256, 128);

    // [q|k|v -> QKVbf (bf16), skip -> out (f32)] = x1 @ [Wq|Wk|Wv|Wskip] + bias2
    k_gemm3<3><<<dim3(313, 4), 256, 0, stream>>>(x1bf, B2t, bias2, nullptr, (void*)QKVbf, out,
                                                 NNODES, 1024, 256);

    // fused attention (gather, online softmax)
    k_attn<<<(NNODES + 3) / 4, 256, 0, stream>>>(QKVbf, csr, startv, deg, out);

    k_bnstats<<<200, 256, 0, stream>>>(out, sums, sumsq);
    k_bnapply<<<(NNODES * 64 + 255) / 256, 256, 0, stream>>>((float4*)out, sums, sumsq, gamma, beta);
}

// Round 7
// 289.296 us; speedup vs baseline: 1.2070x; 1.2070x over previous
//
#include <hip/hip_runtime.h>
#include <math.h>

#define NNODES 20000
#define NEDGES 320000
#define RREL 8
#define EPSBN 1e-5f

typedef float f32x4 __attribute__((ext_vector_type(4)));
typedef __bf16 bf16x8 __attribute__((ext_vector_type(8)));
typedef unsigned short u16x8 __attribute__((ext_vector_type(8)));

static __device__ __forceinline__ unsigned short f2bf(float f) {
    unsigned int x = __builtin_bit_cast(unsigned int, f);
    unsigned int r = x + 0x7FFFu + ((x >> 16) & 1u);
    return (unsigned short)(r >> 16);
}
static __device__ __forceinline__ float bf2f(unsigned short u) {
    unsigned int x = ((unsigned int)u) << 16;
    return __builtin_bit_cast(float, x);
}

// ---------------- CSR build ----------------
__global__ __launch_bounds__(256) void k_count(const int* __restrict__ dst, const int* __restrict__ et,
                                               int* __restrict__ cnt) {
    int e = blockIdx.x * 256 + threadIdx.x;
    if (e >= NEDGES) return;
    atomicAdd(&cnt[dst[e] * RREL + et[e]], 1);
}

__global__ __launch_bounds__(256) void k_invdeg(const int* __restrict__ cnt, float* __restrict__ inv,
                                                int* __restrict__ deg) {
    int i = blockIdx.x * 256 + threadIdx.x;
    if (i >= NNODES) return;
    const int4* p = (const int4*)(cnt + i * 8);
    int4 a = p[0], b = p[1];
    deg[i] = a.x + a.y + a.z + a.w + b.x + b.y + b.z + b.w;
    float4 i0, i1;
    i0.x = 1.0f / (float)(a.x > 0 ? a.x : 1);
    i0.y = 1.0f / (float)(a.y > 0 ? a.y : 1);
    i0.z = 1.0f / (float)(a.z > 0 ? a.z : 1);
    i0.w = 1.0f / (float)(a.w > 0 ? a.w : 1);
    i1.x = 1.0f / (float)(b.x > 0 ? b.x : 1);
    i1.y = 1.0f / (float)(b.y > 0 ? b.y : 1);
    i1.z = 1.0f / (float)(b.z > 0 ? b.z : 1);
    i1.w = 1.0f / (float)(b.w > 0 ? b.w : 1);
    ((float4*)(inv + i * 8))[0] = i0;
    ((float4*)(inv + i * 8))[1] = i1;
}

// single-block exclusive scan, vectorized int4 (256 threads x 80 nodes)
__global__ __launch_bounds__(256) void k_scan(const int* __restrict__ deg, int* __restrict__ start,
                                              int* __restrict__ cursor) {
    __shared__ int part[256];
    int t = threadIdx.x;
    int i0 = t * 80;
    int s = 0;
    if (i0 < NNODES) {
        for (int i = 0; i < 80; i += 4) {
            int4 v = *(const int4*)(deg + i0 + i);
            s += v.x + v.y + v.z + v.w;
        }
    }
    part[t] = s;
    __syncthreads();
    if (t == 0) {
        int acc = 0;
        for (int j = 0; j < 256; j++) { int v = part[j]; part[j] = acc; acc += v; }
    }
    __syncthreads();
    int acc = part[t];
    if (i0 < NNODES) {
        for (int i = 0; i < 80; i += 4) {
            int4 v = *(const int4*)(deg + i0 + i);
            int4 st;
            st.x = acc; acc += v.x;
            st.y = acc; acc += v.y;
            st.z = acc; acc += v.z;
            st.w = acc; acc += v.w;
            *(int4*)(start + i0 + i) = st;
            *(int4*)(cursor + i0 + i) = st;
        }
    }
}

__global__ __launch_bounds__(256) void k_fill(const int* __restrict__ src, const int* __restrict__ dst,
                                              const int* __restrict__ et, int* __restrict__ cursor,
                                              int* __restrict__ csr) {
    int e = blockIdx.x * 256 + threadIdx.x;
    if (e >= NEDGES) return;
    int pos = atomicAdd(&cursor[dst[e]], 1);
    csr[pos] = src[e] * 8 + et[e];
}

// ---------------- fused prep: x->bf16, BrelRoot (2304x256), B2t ----------------
#define PR0 (NNODES * 32)       // x -> bf16, 8 elems each
#define PR1 (2048 * 256)        // Brel -> BrelRoot[0..2048)
#define PR2 (256 * 256)         // Broot -> BrelRoot[2048..2304)
#define PR3 (1024 * 256)        // B2t (+bias2)
__global__ __launch_bounds__(256) void k_prep(const float* __restrict__ x, const float* __restrict__ Wrel,
                                              const float* __restrict__ Wroot,
                                              const float* __restrict__ Wq, const float* __restrict__ Wk,
                                              const float* __restrict__ Wv, const float* __restrict__ Ws,
                                              const float* __restrict__ bq, const float* __restrict__ bk,
                                              const float* __restrict__ bv, const float* __restrict__ bs,
                                              unsigned short* __restrict__ xb, unsigned short* __restrict__ BrelRoot,
                                              unsigned short* __restrict__ B2t, float* __restrict__ bias2) {
    int i = blockIdx.x * 256 + threadIdx.x;
    if (i < PR0) {
        const float4* p = (const float4*)(x + (size_t)i * 8);
        float4 v0 = p[0], v1 = p[1];
        u16x8 w;
        w[0] = f2bf(v0.x); w[1] = f2bf(v0.y); w[2] = f2bf(v0.z); w[3] = f2bf(v0.w);
        w[4] = f2bf(v1.x); w[5] = f2bf(v1.y); w[6] = f2bf(v1.z); w[7] = f2bf(v1.w);
        *(u16x8*)(xb + (size_t)i * 8) = w;
    } else if (i < PR0 + PR1) {
        int idx = i - PR0;
        int col = idx >> 8, g = idx & 255;
        int r = col >> 8, h = col & 255;
        BrelRoot[idx] = f2bf(Wrel[(size_t)r * 65536 + (size_t)g * 256 + h]);
    } else if (i < PR0 + PR1 + PR2) {
        int idx = i - PR0 - PR1;
        int h = idx >> 8, g = idx & 255;
        BrelRoot[(size_t)2048 * 256 + idx] = f2bf(Wroot[(size_t)g * 256 + h]);
    } else {
        int idx = i - PR0 - PR1 - PR2;
        int c = idx >> 8, g = idx & 255;
        const float* W = (c < 256) ? Wq : (c < 512) ? Wk : (c < 768) ? Wv : Ws;
        int cc = c & 255;
        B2t[idx] = f2bf(W[(size_t)g * 256 + cc]);
        if (g == 0) {
            const float* B = (c < 256) ? bq : (c < 512) ? bk : (c < 768) ? bv : bs;
            bias2[c] = B[cc];
        }
    }
}

// ---------------- bf16 MFMA GEMM v4: m97-style 128x128 tile ----------------
// A[M,256] bf16; Bt[Ncols,256] bf16 pre-transposed. 4 waves, each 64x64 out (4x4 frags).
// BK=32, 8 k-steps, single-buffered padded LDS ([128][40]: conflict-free ds_read_b128),
// reg double-buffer: next k-tile's global loads issued before the MFMA cluster.
// MODE 3: col<768 -> bf16 C + bias; col>=768 -> f32 C2 + bias   (QKV | skip)
// MODE 4: col<2048 -> bf16 C (no bias); col>=2048 -> f32 C2 + bias   (Yall | xroot+b1)
template<int MODE>
__global__ __launch_bounds__(256) void k_gemm4(const unsigned short* __restrict__ A,
                                               const unsigned short* __restrict__ Bt,
                                               const float* __restrict__ bias,
                                               unsigned short* __restrict__ C, float* __restrict__ C2,
                                               int M) {
    __shared__ __align__(16) unsigned short As[128][40];
    __shared__ __align__(16) unsigned short Bs[128][40];
    int tid = threadIdx.x;
    int lane = tid & 63, wid = tid >> 6;
    int wr = wid >> 1, wc = wid & 1;
    int lr = lane & 15, lq = lane >> 4;
    int brow = blockIdx.x * 128, bcol = blockIdx.y * 128;

    int srow = tid >> 1;             // 0..127
    int sseg = (tid & 1) * 16;       // elem offset 0/16 within the 32-wide k-slab
    const unsigned short* gA = A + (size_t)(brow + srow) * 256 + sseg;
    const unsigned short* gB = Bt + (size_t)(bcol + srow) * 256 + sseg;
    bool aok = (brow + srow) < M;
    const u16x8 zz = {0, 0, 0, 0, 0, 0, 0, 0};

    u16x8 ra0 = aok ? *(const u16x8*)(gA) : zz;
    u16x8 ra1 = aok ? *(const u16x8*)(gA + 8) : zz;
    u16x8 rb0 = *(const u16x8*)(gB);
    u16x8 rb1 = *(const u16x8*)(gB + 8);

    f32x4 acc[4][4];
    #pragma unroll
    for (int i = 0; i < 4; i++)
        #pragma unroll
        for (int j = 0; j < 4; j++) acc[i][j] = (f32x4){0.f, 0.f, 0.f, 0.f};

    for (int ks = 0; ks < 8; ks++) {
        if (ks) __syncthreads();              // prior reads done before overwrite
        *(u16x8*)&As[srow][sseg] = ra0;
        *(u16x8*)&As[srow][sseg + 8] = ra1;
        *(u16x8*)&Bs[srow][sseg] = rb0;
        *(u16x8*)&Bs[srow][sseg + 8] = rb1;
        __syncthreads();
        if (ks < 7) {                          // issue next tile; in flight during MFMA
            const unsigned short* pa = gA + (ks + 1) * 32;
            const unsigned short* pb = gB + (ks + 1) * 32;
            ra0 = aok ? *(const u16x8*)(pa) : zz;
            ra1 = aok ? *(const u16x8*)(pa + 8) : zz;
            rb0 = *(const u16x8*)(pb);
            rb1 = *(const u16x8*)(pb + 8);
        }
        bf16x8 af[4], bfr[4];
        #pragma unroll
        for (int f = 0; f < 4; f++) {
            af[f] = *(const bf16x8*)&As[wr * 64 + f * 16 + lr][lq * 8];
            bfr[f] = *(const bf16x8*)&Bs[wc * 64 + f * 16 + lr][lq * 8];
        }
        #pragma unroll
        for (int i = 0; i < 4; i++)
            #pragma unroll
            for (int j = 0; j < 4; j++)
                acc[i][j] = __builtin_amdgcn_mfma_f32_16x16x32_bf16(af[i], bfr[j], acc[i][j], 0, 0, 0);
    }

    // epilogue: C/D layout col=lane&15, row=(lane>>4)*4+reg
    #pragma unroll
    for (int i = 0; i < 4; i++) {
        int row = brow + wr * 64 + i * 16 + lq * 4;
        #pragma unroll
        for (int j = 0; j < 4; j++) {
            int col = bcol + wc * 64 + j * 16 + lr;
            #pragma unroll
            for (int r = 0; r < 4; r++) {
                int gr = row + r;
                if (gr >= M) continue;
                float v = acc[i][j][r];
                if (MODE == 4) {
                    if (col < 2048) C[(size_t)gr * 2048 + col] = f2bf(v);
                    else            C2[(size_t)gr * 256 + (col - 2048)] = v + bias[col - 2048];
                } else {  // MODE 3
                    v += bias[col];
                    if (col < 768) C[(size_t)gr * 768 + col] = f2bf(v);
                    else           C2[(size_t)gr * 256 + (col - 768)] = v;
                }
            }
        }
    }
}

// ---------------- RGCN aggregate + root add: x1bf = bf16(xroot + sum inv*Yall[src,r]) ----------------
__global__ __launch_bounds__(256) void k_rgcn(const unsigned short* __restrict__ Yall, const int* __restrict__ csr,
                                              const int* __restrict__ start, const int* __restrict__ deg,
                                              const float* __restrict__ inv, const float* __restrict__ xroot,
                                              unsigned short* __restrict__ x1bf) {
    int node = blockIdx.x * 4 + (threadIdx.x >> 6);
    int lane = threadIdx.x & 63;
    if (node >= NNODES) return;
    int s0 = start[node], n = deg[node];
    float4 acc = ((const float4*)(xroot + (size_t)node * 256))[lane];
    int j = 0;
    for (; j + 4 <= n; j += 4) {
        int p0 = csr[s0 + j], p1 = csr[s0 + j + 1], p2 = csr[s0 + j + 2], p3 = csr[s0 + j + 3];
        float c0 = inv[node * RREL + (p0 & 7)];
        float c1 = inv[node * RREL + (p1 & 7)];
        float c2 = inv[node * RREL + (p2 & 7)];
        float c3 = inv[node * RREL + (p3 & 7)];
        ushort4 y0 = *(const ushort4*)(Yall + (size_t)(p0 >> 3) * 2048 + (p0 & 7) * 256 + lane * 4);
        ushort4 y1 = *(const ushort4*)(Yall + (size_t)(p1 >> 3) * 2048 + (p1 & 7) * 256 + lane * 4);
        ushort4 y2 = *(const ushort4*)(Yall + (size_t)(p2 >> 3) * 2048 + (p2 & 7) * 256 + lane * 4);
        ushort4 y3 = *(const ushort4*)(Yall + (size_t)(p3 >> 3) * 2048 + (p3 & 7) * 256 + lane * 4);
        acc.x += c0 * bf2f(y0.x) + c1 * bf2f(y1.x) + c2 * bf2f(y2.x) + c3 * bf2f(y3.x);
        acc.y += c0 * bf2f(y0.y) + c1 * bf2f(y1.y) + c2 * bf2f(y2.y) + c3 * bf2f(y3.y);
        acc.z += c0 * bf2f(y0.z) + c1 * bf2f(y1.z) + c2 * bf2f(y2.z) + c3 * bf2f(y3.z);
        acc.w += c0 * bf2f(y0.w) + c1 * bf2f(y1.w) + c2 * bf2f(y2.w) + c3 * bf2f(y3.w);
    }
    for (; j < n; j++) {
        int pk = csr[s0 + j];
        float sc = inv[node * RREL + (pk & 7)];
        ushort4 y = *(const ushort4*)(Yall + (size_t)(pk >> 3) * 2048 + (pk & 7) * 256 + lane * 4);
        acc.x += sc * bf2f(y.x);
        acc.y += sc * bf2f(y.y);
        acc.z += sc * bf2f(y.z);
        acc.w += sc * bf2f(y.w);
    }
    ushort4 o;
    o.x = f2bf(acc.x); o.y = f2bf(acc.y); o.z = f2bf(acc.z); o.w = f2bf(acc.w);
    *(ushort4*)(x1bf + (size_t)node * 256 + lane * 4) = o;
}

// ---------------- fused attention: one wave per node, online softmax, edges batched x4 ----------------
__global__ __launch_bounds__(256) void k_attn(const unsigned short* __restrict__ QKV, const int* __restrict__ csr,
                                              const int* __restrict__ start, const int* __restrict__ deg,
                                              float* __restrict__ out) {
    int node = blockIdx.x * 4 + (threadIdx.x >> 6);
    int lane = threadIdx.x & 63;
    if (node >= NNODES) return;
    int s0 = start[node], n = deg[node];
    if (n == 0) return;
    ushort4 qu = *(const ushort4*)(QKV + (size_t)node * 768 + lane * 4);
    float q0 = bf2f(qu.x), q1 = bf2f(qu.y), q2 = bf2f(qu.z), q3 = bf2f(qu.w);
    float m = -INFINITY, den = 0.f;
    float4 acc = make_float4(0.f, 0.f, 0.f, 0.f);
    int j = 0;
    for (; j + 4 <= n; j += 4) {
        const unsigned short* b0 = QKV + (size_t)(csr[s0 + j] >> 3) * 768;
        const unsigned short* b1 = QKV + (size_t)(csr[s0 + j + 1] >> 3) * 768;
        const unsigned short* b2 = QKV + (size_t)(csr[s0 + j + 2] >> 3) * 768;
        const unsigned short* b3 = QKV + (size_t)(csr[s0 + j + 3] >> 3) * 768;
        ushort4 k0 = *(const ushort4*)(b0 + 256 + lane * 4);
        ushort4 k1 = *(const ushort4*)(b1 + 256 + lane * 4);
        ushort4 k2 = *(const ushort4*)(b2 + 256 + lane * 4);
        ushort4 k3 = *(const ushort4*)(b3 + 256 + lane * 4);
        ushort4 v0 = *(const ushort4*)(b0 + 512 + lane * 4);
        ushort4 v1 = *(const ushort4*)(b1 + 512 + lane * 4);
        ushort4 v2 = *(const ushort4*)(b2 + 512 + lane * 4);
        ushort4 v3 = *(const ushort4*)(b3 + 512 + lane * 4);
        float p0 = q0 * bf2f(k0.x) + q1 * bf2f(k0.y) + q2 * bf2f(k0.z) + q3 * bf2f(k0.w);
        float p1 = q0 * bf2f(k1.x) + q1 * bf2f(k1.y) + q2 * bf2f(k1.z) + q3 * bf2f(k1.w);
        float p2 = q0 * bf2f(k2.x) + q1 * bf2f(k2.y) + q2 * bf2f(k2.z) + q3 * bf2f(k2.w);
        float p3 = q0 * bf2f(k3.x) + q1 * bf2f(k3.y) + q2 * bf2f(k3.z) + q3 * bf2f(k3.w);
        #pragma unroll
        for (int o = 32; o; o >>= 1) {
            p0 += __shfl_xor(p0, o);
            p1 += __shfl_xor(p1, o);
            p2 += __shfl_xor(p2, o);
            p3 += __shfl_xor(p3, o);
        }
        p0 *= 0.0625f; p1 *= 0.0625f; p2 *= 0.0625f; p3 *= 0.0625f;
        float pm = fmaxf(fmaxf(p0, p1), fmaxf(p2, p3));
        if (pm > m) {
            float rr = __expf(m - pm);
            den *= rr;
            acc.x *= rr; acc.y *= rr; acc.z *= rr; acc.w *= rr;
            m = pm;
        }
        float e0 = __expf(p0 - m), e1 = __expf(p1 - m), e2 = __expf(p2 - m), e3 = __expf(p3 - m);
        den += e0 + e1 + e2 + e3;
        acc.x += e0 * bf2f(v0.x) + e1 * bf2f(v1.x) + e2 * bf2f(v2.x) + e3 * bf2f(v3.x);
        acc.y += e0 * bf2f(v0.y) + e1 * bf2f(v1.y) + e2 * bf2f(v2.y) + e3 * bf2f(v3.y);
        acc.z += e0 * bf2f(v0.z) + e1 * bf2f(v1.z) + e2 * bf2f(v2.z) + e3 * bf2f(v3.z);
        acc.w += e0 * bf2f(v0.w) + e1 * bf2f(v1.w) + e2 * bf2f(v2.w) + e3 * bf2f(v3.w);
    }
    for (; j < n; j++) {
        const unsigned short* base = QKV + (size_t)(csr[s0 + j] >> 3) * 768;
        ushort4 ku = *(const ushort4*)(base + 256 + lane * 4);
        ushort4 vu = *(const ushort4*)(base + 512 + lane * 4);
        float p = q0 * bf2f(ku.x) + q1 * bf2f(ku.y) + q2 * bf2f(ku.z) + q3 * bf2f(ku.w);
        #pragma unroll
        for (int o = 32; o; o >>= 1) p += __shfl_xor(p, o);
        p *= 0.0625f;
        if (p > m) {
            float rr = __expf(m - p);
            den *= rr;
            acc.x *= rr; acc.y *= rr; acc.z *= rr; acc.w *= rr;
            m = p;
        }
        float ex = __expf(p - m);
        den += ex;
        acc.x += ex * bf2f(vu.x); acc.y += ex * bf2f(vu.y);
        acc.z += ex * bf2f(vu.z); acc.w += ex * bf2f(vu.w);
    }
    float rinv = 1.0f / fmaxf(den, 1e-16f);
    float4* o4 = (float4*)(out + (size_t)node * 256);
    float4 o = o4[lane];
    o.x += acc.x * rinv; o.y += acc.y * rinv; o.z += acc.z * rinv; o.w += acc.w * rinv;
    o4[lane] = o;
}

// ---------------- batch norm + leaky relu ----------------
__global__ __launch_bounds__(256) void k_bnstats(const float* __restrict__ out, float* __restrict__ sums,
                                                 float* __restrict__ sumsq) {
    int c = threadIdx.x;
    int rows_per = (NNODES + gridDim.x - 1) / gridDim.x;
    int r0 = blockIdx.x * rows_per;
    int r1 = r0 + rows_per; if (r1 > NNODES) r1 = NNODES;
    float s = 0.f, ss = 0.f;
    for (int r = r0; r < r1; r++) {
        float v = out[(size_t)r * 256 + c];
        s += v; ss += v * v;
    }
    atomicAdd(&sums[c], s);
    atomicAdd(&sumsq[c], ss);
}

__global__ __launch_bounds__(256) void k_bnapply(float4* __restrict__ out, const float* __restrict__ sums,
                                                 const float* __restrict__ sumsq, const float* __restrict__ gamma,
                                                 const float* __restrict__ beta) {
    int i = blockIdx.x * 256 + threadIdx.x;
    if (i >= NNODES * 64) return;
    int c4 = i & 63;
    float4 sc, sh;
    #pragma unroll
    for (int t = 0; t < 4; t++) {
        int c = c4 * 4 + t;
        float mu = sums[c] * (1.0f / NNODES);
        float var = sumsq[c] * (1.0f / NNODES) - mu * mu;
        float s = gamma[c] * rsqrtf(fmaxf(var, 0.f) + EPSBN);
        ((float*)&sc)[t] = s;
        ((float*)&sh)[t] = beta[c] - mu * s;
    }
    float4 v = out[i];
    v.x = v.x * sc.x + sh.x; v.y = v.y * sc.y + sh.y;
    v.z = v.z * sc.z + sh.z; v.w = v.w * sc.w + sh.w;
    v.x = v.x > 0.f ? v.x : 0.01f * v.x;
    v.y = v.y > 0.f ? v.y : 0.01f * v.y;
    v.z = v.z > 0.f ? v.z : 0.01f * v.z;
    v.w = v.w > 0.f ? v.w : 0.01f * v.w;
    out[i] = v;
}

extern "C" void kernel_launch(void* const* d_in, const int* in_sizes, int n_in,
                              void* d_out, int out_size, void* d_ws, size_t ws_size,
                              hipStream_t stream) {
    const float* x = (const float*)d_in[0];
    const int* ei = (const int*)d_in[1];
    const int* etype = (const int*)d_in[2];
    const float* Wrel = (const float*)d_in[3];
    const float* Wroot = (const float*)d_in[4];
    const float* b1 = (const float*)d_in[5];
    const float* Wq = (const float*)d_in[6];
    const float* bq = (const float*)d_in[7];
    const float* Wk = (const float*)d_in[8];
    const float* bk = (const float*)d_in[9];
    const float* Wv = (const float*)d_in[10];
    const float* bv = (const float*)d_in[11];
    const float* Ws = (const float*)d_in[12];
    const float* bs = (const float*)d_in[13];
    const float* gamma = (const float*)d_in[14];
    const float* beta = (const float*)d_in[15];
    float* out = (float*)d_out;

    const int* srcA = ei;
    const int* dstA = ei + NEDGES;

    char* w = (char*)d_ws;
    unsigned short* Yall = (unsigned short*)w;  w += (size_t)NNODES * 2048 * 2;  // 81.9 MB
    unsigned short* x_bf = (unsigned short*)w;  w += (size_t)NNODES * 256 * 2;   // 10.2 MB
    unsigned short* x1bf = (unsigned short*)w;  w += (size_t)NNODES * 256 * 2;   // 10.2 MB
    float* xroot = (float*)w;                   w += (size_t)NNODES * 256 * 4;   // 20.5 MB
    unsigned short* QKVbf = (unsigned short*)w; w += (size_t)NNODES * 768 * 2;   // 30.7 MB
    unsigned short* BrelRoot = (unsigned short*)w; w += (size_t)2304 * 256 * 2;  //  1.2 MB
    unsigned short* B2t = (unsigned short*)w;   w += (size_t)1024 * 256 * 2;
    float* bias2 = (float*)w;                   w += 1024 * 4;
    int* cnt = (int*)w;                         w += (size_t)NNODES * RREL * 4;
    float* invc = (float*)w;                    w += (size_t)NNODES * RREL * 4;
    int* deg = (int*)w;                         w += (size_t)NNODES * 4;
    int* startv = (int*)w;                      w += (size_t)NNODES * 4;
    int* cursor = (int*)w;                      w += (size_t)NNODES * 4;
    int* csr = (int*)w;                         w += (size_t)NEDGES * 4;
    float* sums = (float*)w;                    w += 1024;
    float* sumsq = (float*)w;                   w += 1024;
    size_t need = (size_t)(w - (char*)d_ws);
    if (ws_size < need) return;

    hipMemsetAsync(cnt, 0, (size_t)NNODES * RREL * 4, stream);
    hipMemsetAsync(sums, 0, 2048, stream);

    k_count<<<(NEDGES + 255) / 256, 256, 0, stream>>>(dstA, etype, cnt);
    k_invdeg<<<(NNODES + 255) / 256, 256, 0, stream>>>(cnt, invc, deg);
    k_scan<<<1, 256, 0, stream>>>(deg, startv, cursor);
    k_fill<<<(NEDGES + 255) / 256, 256, 0, stream>>>(srcA, dstA, etype, cursor, csr);

    k_prep<<<(PR0 + PR1 + PR2 + PR3) / 256, 256, 0, stream>>>(x, Wrel, Wroot, Wq, Wk, Wv, Ws,
                                                              bq, bk, bv, bs, x_bf, BrelRoot, B2t, bias2);

    // [Yall (bf16, cols<2048) | xroot=acc+b1 (f32)] = x_bf @ [W_0|...|W_7|W_root]
    k_gemm4<4><<<dim3(157, 18), 256, 0, stream>>>(x_bf, BrelRoot, b1, Yall, xroot, NNODES);

    // x1bf = bf16(xroot + sum_r inv * Yall[src, r])
    k_rgcn<<<(NNODES + 3) / 4, 256, 0, stream>>>(Yall, csr, startv, deg, invc, xroot, x1bf);

    // [q|k|v -> QKVbf (bf16), skip -> out (f32)] = x1 @ [Wq|Wk|Wv|Wskip] + bias2
    k_gemm4<3><<<dim3(157, 8), 256, 0, stream>>>(x1bf, B2t, bias2, QKVbf, out, NNODES);

    // fused attention (gather, online softmax)
    k_attn<<<(NNODES + 3) / 4, 256, 0, stream>>>(QKVbf, csr, startv, deg, out);

    k_bnstats<<<400, 256, 0, stream>>>(out, sums, sumsq);
    k_bnapply<<<(NNODES * 64 + 255) / 256, 256, 0, stream>>>((float4*)out, sums, sumsq, gamma, beta);
}

// Round 8
// 274.534 us; speedup vs baseline: 1.2719x; 1.0538x over previous
//
#include <hip/hip_runtime.h>
#include <math.h>

#define NNODES 20000
#define NEDGES 320000
#define RREL 8
#define EPSBN 1e-5f

typedef float f32x4 __attribute__((ext_vector_type(4)));
typedef __bf16 bf16x8 __attribute__((ext_vector_type(8)));
typedef unsigned short u16x8 __attribute__((ext_vector_type(8)));

static __device__ __forceinline__ unsigned short f2bf(float f) {
    unsigned int x = __builtin_bit_cast(unsigned int, f);
    unsigned int r = x + 0x7FFFu + ((x >> 16) & 1u);
    return (unsigned short)(r >> 16);
}
static __device__ __forceinline__ float bf2f(unsigned short u) {
    unsigned int x = ((unsigned int)u) << 16;
    return __builtin_bit_cast(float, x);
}

// ---------------- CSR build ----------------
__global__ __launch_bounds__(256) void k_count(const int* __restrict__ dst, const int* __restrict__ et,
                                               int* __restrict__ cnt) {
    int e = blockIdx.x * 256 + threadIdx.x;
    if (e >= NEDGES) return;
    atomicAdd(&cnt[dst[e] * RREL + et[e]], 1);
}

__global__ __launch_bounds__(256) void k_invdeg(const int* __restrict__ cnt, float* __restrict__ inv,
                                                int* __restrict__ deg) {
    int i = blockIdx.x * 256 + threadIdx.x;
    if (i >= NNODES) return;
    const int4* p = (const int4*)(cnt + i * 8);
    int4 a = p[0], b = p[1];
    deg[i] = a.x + a.y + a.z + a.w + b.x + b.y + b.z + b.w;
    float4 i0, i1;
    i0.x = 1.0f / (float)(a.x > 0 ? a.x : 1);
    i0.y = 1.0f / (float)(a.y > 0 ? a.y : 1);
    i0.z = 1.0f / (float)(a.z > 0 ? a.z : 1);
    i0.w = 1.0f / (float)(a.w > 0 ? a.w : 1);
    i1.x = 1.0f / (float)(b.x > 0 ? b.x : 1);
    i1.y = 1.0f / (float)(b.y > 0 ? b.y : 1);
    i1.z = 1.0f / (float)(b.z > 0 ? b.z : 1);
    i1.w = 1.0f / (float)(b.w > 0 ? b.w : 1);
    ((float4*)(inv + i * 8))[0] = i0;
    ((float4*)(inv + i * 8))[1] = i1;
}

__global__ __launch_bounds__(256) void k_scan(const int* __restrict__ deg, int* __restrict__ start,
                                              int* __restrict__ cursor) {
    __shared__ int part[256];
    int t = threadIdx.x;
    int i0 = t * 80;
    int s = 0;
    if (i0 < NNODES) {
        for (int i = 0; i < 80; i += 4) {
            int4 v = *(const int4*)(deg + i0 + i);
            s += v.x + v.y + v.z + v.w;
        }
    }
    part[t] = s;
    __syncthreads();
    if (t == 0) {
        int acc = 0;
        for (int j = 0; j < 256; j++) { int v = part[j]; part[j] = acc; acc += v; }
    }
    __syncthreads();
    int acc = part[t];
    if (i0 < NNODES) {
        for (int i = 0; i < 80; i += 4) {
            int4 v = *(const int4*)(deg + i0 + i);
            int4 st;
            st.x = acc; acc += v.x;
            st.y = acc; acc += v.y;
            st.z = acc; acc += v.z;
            st.w = acc; acc += v.w;
            *(int4*)(start + i0 + i) = st;
            *(int4*)(cursor + i0 + i) = st;
        }
    }
}

__global__ __launch_bounds__(256) void k_fill(const int* __restrict__ src, const int* __restrict__ dst,
                                              const int* __restrict__ et, int* __restrict__ cursor,
                                              int* __restrict__ csr) {
    int e = blockIdx.x * 256 + threadIdx.x;
    if (e >= NEDGES) return;
    int pos = atomicAdd(&cursor[dst[e]], 1);
    csr[pos] = src[e] * 8 + et[e];
}

// ---------------- fused prep ----------------
#define PR0 (NNODES * 32)
#define PR1 (2048 * 256)
#define PR2 (256 * 256)
#define PR3 (1024 * 256)
__global__ __launch_bounds__(256) void k_prep(const float* __restrict__ x, const float* __restrict__ Wrel,
                                              const float* __restrict__ Wroot,
                                              const float* __restrict__ Wq, const float* __restrict__ Wk,
                                              const float* __restrict__ Wv, const float* __restrict__ Ws,
                                              const float* __restrict__ bq, const float* __restrict__ bk,
                                              const float* __restrict__ bv, const float* __restrict__ bs,
                                              unsigned short* __restrict__ xb, unsigned short* __restrict__ BrelRoot,
                                              unsigned short* __restrict__ B2t, float* __restrict__ bias2) {
    int i = blockIdx.x * 256 + threadIdx.x;
    if (i < PR0) {
        const float4* p = (const float4*)(x + (size_t)i * 8);
        float4 v0 = p[0], v1 = p[1];
        u16x8 w;
        w[0] = f2bf(v0.x); w[1] = f2bf(v0.y); w[2] = f2bf(v0.z); w[3] = f2bf(v0.w);
        w[4] = f2bf(v1.x); w[5] = f2bf(v1.y); w[6] = f2bf(v1.z); w[7] = f2bf(v1.w);
        *(u16x8*)(xb + (size_t)i * 8) = w;
    } else if (i < PR0 + PR1) {
        int idx = i - PR0;
        int col = idx >> 8, g = idx & 255;
        int r = col >> 8, h = col & 255;
        BrelRoot[idx] = f2bf(Wrel[(size_t)r * 65536 + (size_t)g * 256 + h]);
    } else if (i < PR0 + PR1 + PR2) {
        int idx = i - PR0 - PR1;
        int h = idx >> 8, g = idx & 255;
        BrelRoot[(size_t)2048 * 256 + idx] = f2bf(Wroot[(size_t)g * 256 + h]);
    } else {
        int idx = i - PR0 - PR1 - PR2;
        int c = idx >> 8, g = idx & 255;
        const float* W = (c < 256) ? Wq : (c < 512) ? Wk : (c < 768) ? Wv : Ws;
        int cc = c & 255;
        B2t[idx] = f2bf(W[(size_t)g * 256 + cc]);
        if (g == 0) {
            const float* B = (c < 256) ? bq : (c < 512) ? bk : (c < 768) ? bv : bs;
            bias2[c] = B[cc];
        }
    }
}

// ---------------- bf16 MFMA GEMM v5: 128x128 tile + XCD-aware bijective swizzle (T1/m204) ----------------
// 1-D grid of nwg = nRowT*nct blocks. xcd = bid&7 owns a contiguous chunk of tile
// indices ordered (rowTile-major, colTile inner) -> A-panel L2-resident per XCD.
// MODE 3: col<768 -> bf16 C + bias; col>=768 -> f32 C2 + bias   (QKV | skip)
// MODE 4: col<2048 -> bf16 C; col>=2048 -> f32 C2 + bias         (Yall | xroot+b1)
template<int MODE>
__global__ __launch_bounds__(256) void k_gemm5(const unsigned short* __restrict__ A,
                                               const unsigned short* __restrict__ Bt,
                                               const float* __restrict__ bias,
                                               unsigned short* __restrict__ C, float* __restrict__ C2,
                                               int M, int nct, int q, int rr) {
    // bijective XCD swizzle (m204)
    int bid = blockIdx.x;
    int xcd = bid & 7, idx = bid >> 3;
    int base = (xcd < rr) ? xcd * (q + 1) : rr * (q + 1) + (xcd - rr) * q;
    int nid = base + idx;
    int rowT = nid / nct, colT = nid - rowT * nct;
    int brow = rowT * 128, bcol = colT * 128;

    __shared__ __align__(16) unsigned short As[128][40];
    __shared__ __align__(16) unsigned short Bs[128][40];
    int tid = threadIdx.x;
    int lane = tid & 63, wid = tid >> 6;
    int wr = wid >> 1, wc = wid & 1;
    int lr = lane & 15, lq = lane >> 4;

    int srow = tid >> 1;
    int sseg = (tid & 1) * 16;
    const unsigned short* gA = A + (size_t)(brow + srow) * 256 + sseg;
    const unsigned short* gB = Bt + (size_t)(bcol + srow) * 256 + sseg;
    bool aok = (brow + srow) < M;
    const u16x8 zz = {0, 0, 0, 0, 0, 0, 0, 0};

    u16x8 ra0 = aok ? *(const u16x8*)(gA) : zz;
    u16x8 ra1 = aok ? *(const u16x8*)(gA + 8) : zz;
    u16x8 rb0 = *(const u16x8*)(gB);
    u16x8 rb1 = *(const u16x8*)(gB + 8);

    f32x4 acc[4][4];
    #pragma unroll
    for (int i = 0; i < 4; i++)
        #pragma unroll
        for (int j = 0; j < 4; j++) acc[i][j] = (f32x4){0.f, 0.f, 0.f, 0.f};

    for (int ks = 0; ks < 8; ks++) {
        if (ks) __syncthreads();
        *(u16x8*)&As[srow][sseg] = ra0;
        *(u16x8*)&As[srow][sseg + 8] = ra1;
        *(u16x8*)&Bs[srow][sseg] = rb0;
        *(u16x8*)&Bs[srow][sseg + 8] = rb1;
        __syncthreads();
        if (ks < 7) {
            const unsigned short* pa = gA + (ks + 1) * 32;
            const unsigned short* pb = gB + (ks + 1) * 32;
            ra0 = aok ? *(const u16x8*)(pa) : zz;
            ra1 = aok ? *(const u16x8*)(pa + 8) : zz;
            rb0 = *(const u16x8*)(pb);
            rb1 = *(const u16x8*)(pb + 8);
        }
        bf16x8 af[4], bfr[4];
        #pragma unroll
        for (int f = 0; f < 4; f++) {
            af[f] = *(const bf16x8*)&As[wr * 64 + f * 16 + lr][lq * 8];
            bfr[f] = *(const bf16x8*)&Bs[wc * 64 + f * 16 + lr][lq * 8];
        }
        #pragma unroll
        for (int i = 0; i < 4; i++)
            #pragma unroll
            for (int j = 0; j < 4; j++)
                acc[i][j] = __builtin_amdgcn_mfma_f32_16x16x32_bf16(af[i], bfr[j], acc[i][j], 0, 0, 0);
    }

    #pragma unroll
    for (int i = 0; i < 4; i++) {
        int row = brow + wr * 64 + i * 16 + lq * 4;
        #pragma unroll
        for (int j = 0; j < 4; j++) {
            int col = bcol + wc * 64 + j * 16 + lr;
            #pragma unroll
            for (int r = 0; r < 4; r++) {
                int gr = row + r;
                if (gr >= M) continue;
                float v = acc[i][j][r];
                if (MODE == 4) {
                    if (col < 2048) C[(size_t)gr * 2048 + col] = f2bf(v);
                    else            C2[(size_t)gr * 256 + (col - 2048)] = v + bias[col - 2048];
                } else {
                    v += bias[col];
                    if (col < 768) C[(size_t)gr * 768 + col] = f2bf(v);
                    else           C2[(size_t)gr * 256 + (col - 768)] = v;
                }
            }
        }
    }
}

// ---------------- RGCN aggregate + root add, edges batched x8 ----------------
__global__ __launch_bounds__(256) void k_rgcn(const unsigned short* __restrict__ Yall, const int* __restrict__ csr,
                                              const int* __restrict__ start, const int* __restrict__ deg,
                                              const float* __restrict__ inv, const float* __restrict__ xroot,
                                              unsigned short* __restrict__ x1bf) {
    int node = blockIdx.x * 4 + (threadIdx.x >> 6);
    int lane = threadIdx.x & 63;
    if (node >= NNODES) return;
    int s0 = start[node], n = deg[node];
    float4 acc = ((const float4*)(xroot + (size_t)node * 256))[lane];
    int j = 0;
    for (; j + 8 <= n; j += 8) {
        int pk[8];
        #pragma unroll
        for (int t = 0; t < 8; t++) pk[t] = csr[s0 + j + t];
        float cc[8];
        ushort4 yy[8];
        #pragma unroll
        for (int t = 0; t < 8; t++) {
            cc[t] = inv[node * RREL + (pk[t] & 7)];
            yy[t] = *(const ushort4*)(Yall + (size_t)(pk[t] >> 3) * 2048 + (pk[t] & 7) * 256 + lane * 4);
        }
        #pragma unroll
        for (int t = 0; t < 8; t++) {
            acc.x += cc[t] * bf2f(yy[t].x);
            acc.y += cc[t] * bf2f(yy[t].y);
            acc.z += cc[t] * bf2f(yy[t].z);
            acc.w += cc[t] * bf2f(yy[t].w);
        }
    }
    for (; j + 4 <= n; j += 4) {
        int p0 = csr[s0 + j], p1 = csr[s0 + j + 1], p2 = csr[s0 + j + 2], p3 = csr[s0 + j + 3];
        float c0 = inv[node * RREL + (p0 & 7)];
        float c1 = inv[node * RREL + (p1 & 7)];
        float c2 = inv[node * RREL + (p2 & 7)];
        float c3 = inv[node * RREL + (p3 & 7)];
        ushort4 y0 = *(const ushort4*)(Yall + (size_t)(p0 >> 3) * 2048 + (p0 & 7) * 256 + lane * 4);
        ushort4 y1 = *(const ushort4*)(Yall + (size_t)(p1 >> 3) * 2048 + (p1 & 7) * 256 + lane * 4);
        ushort4 y2 = *(const ushort4*)(Yall + (size_t)(p2 >> 3) * 2048 + (p2 & 7) * 256 + lane * 4);
        ushort4 y3 = *(const ushort4*)(Yall + (size_t)(p3 >> 3) * 2048 + (p3 & 7) * 256 + lane * 4);
        acc.x += c0 * bf2f(y0.x) + c1 * bf2f(y1.x) + c2 * bf2f(y2.x) + c3 * bf2f(y3.x);
        acc.y += c0 * bf2f(y0.y) + c1 * bf2f(y1.y) + c2 * bf2f(y2.y) + c3 * bf2f(y3.y);
        acc.z += c0 * bf2f(y0.z) + c1 * bf2f(y1.z) + c2 * bf2f(y2.z) + c3 * bf2f(y3.z);
        acc.w += c0 * bf2f(y0.w) + c1 * bf2f(y1.w) + c2 * bf2f(y2.w) + c3 * bf2f(y3.w);
    }
    for (; j < n; j++) {
        int pk = csr[s0 + j];
        float sc = inv[node * RREL + (pk & 7)];
        ushort4 y = *(const ushort4*)(Yall + (size_t)(pk >> 3) * 2048 + (pk & 7) * 256 + lane * 4);
        acc.x += sc * bf2f(y.x);
        acc.y += sc * bf2f(y.y);
        acc.z += sc * bf2f(y.z);
        acc.w += sc * bf2f(y.w);
    }
    ushort4 o;
    o.x = f2bf(acc.x); o.y = f2bf(acc.y); o.z = f2bf(acc.z); o.w = f2bf(acc.w);
    *(ushort4*)(x1bf + (size_t)node * 256 + lane * 4) = o;
}

// ---------------- fused attention: one wave per node, online softmax, edges batched x4 ----------------
__global__ __launch_bounds__(256) void k_attn(const unsigned short* __restrict__ QKV, const int* __restrict__ csr,
                                              const int* __restrict__ start, const int* __restrict__ deg,
                                              float* __restrict__ out) {
    int node = blockIdx.x * 4 + (threadIdx.x >> 6);
    int lane = threadIdx.x & 63;
    if (node >= NNODES) return;
    int s0 = start[node], n = deg[node];
    if (n == 0) return;
    ushort4 qu = *(const ushort4*)(QKV + (size_t)node * 768 + lane * 4);
    float q0 = bf2f(qu.x), q1 = bf2f(qu.y), q2 = bf2f(qu.z), q3 = bf2f(qu.w);
    float m = -INFINITY, den = 0.f;
    float4 acc = make_float4(0.f, 0.f, 0.f, 0.f);
    int j = 0;
    for (; j + 4 <= n; j += 4) {
        const unsigned short* b0 = QKV + (size_t)(csr[s0 + j] >> 3) * 768;
        const unsigned short* b1 = QKV + (size_t)(csr[s0 + j + 1] >> 3) * 768;
        const unsigned short* b2 = QKV + (size_t)(csr[s0 + j + 2] >> 3) * 768;
        const unsigned short* b3 = QKV + (size_t)(csr[s0 + j + 3] >> 3) * 768;
        ushort4 k0 = *(const ushort4*)(b0 + 256 + lane * 4);
        ushort4 k1 = *(const ushort4*)(b1 + 256 + lane * 4);
        ushort4 k2 = *(const ushort4*)(b2 + 256 + lane * 4);
        ushort4 k3 = *(const ushort4*)(b3 + 256 + lane * 4);
        ushort4 v0 = *(const ushort4*)(b0 + 512 + lane * 4);
        ushort4 v1 = *(const ushort4*)(b1 + 512 + lane * 4);
        ushort4 v2 = *(const ushort4*)(b2 + 512 + lane * 4);
        ushort4 v3 = *(const ushort4*)(b3 + 512 + lane * 4);
        float p0 = q0 * bf2f(k0.x) + q1 * bf2f(k0.y) + q2 * bf2f(k0.z) + q3 * bf2f(k0.w);
        float p1 = q0 * bf2f(k1.x) + q1 * bf2f(k1.y) + q2 * bf2f(k1.z) + q3 * bf2f(k1.w);
        float p2 = q0 * bf2f(k2.x) + q1 * bf2f(k2.y) + q2 * bf2f(k2.z) + q3 * bf2f(k2.w);
        float p3 = q0 * bf2f(k3.x) + q1 * bf2f(k3.y) + q2 * bf2f(k3.z) + q3 * bf2f(k3.w);
        #pragma unroll
        for (int o = 32; o; o >>= 1) {
            p0 += __shfl_xor(p0, o);
            p1 += __shfl_xor(p1, o);
            p2 += __shfl_xor(p2, o);
            p3 += __shfl_xor(p3, o);
        }
        p0 *= 0.0625f; p1 *= 0.0625f; p2 *= 0.0625f; p3 *= 0.0625f;
        float pm = fmaxf(fmaxf(p0, p1), fmaxf(p2, p3));
        if (pm > m) {
            float rr = __expf(m - pm);
            den *= rr;
            acc.x *= rr; acc.y *= rr; acc.z *= rr; acc.w *= rr;
            m = pm;
        }
        float e0 = __expf(p0 - m), e1 = __expf(p1 - m), e2 = __expf(p2 - m), e3 = __expf(p3 - m);
        den += e0 + e1 + e2 + e3;
        acc.x += e0 * bf2f(v0.x) + e1 * bf2f(v1.x) + e2 * bf2f(v2.x) + e3 * bf2f(v3.x);
        acc.y += e0 * bf2f(v0.y) + e1 * bf2f(v1.y) + e2 * bf2f(v2.y) + e3 * bf2f(v3.y);
        acc.z += e0 * bf2f(v0.z) + e1 * bf2f(v1.z) + e2 * bf2f(v2.z) + e3 * bf2f(v3.z);
        acc.w += e0 * bf2f(v0.w) + e1 * bf2f(v1.w) + e2 * bf2f(v2.w) + e3 * bf2f(v3.w);
    }
    for (; j < n; j++) {
        const unsigned short* base = QKV + (size_t)(csr[s0 + j] >> 3) * 768;
        ushort4 ku = *(const ushort4*)(base + 256 + lane * 4);
        ushort4 vu = *(const ushort4*)(base + 512 + lane * 4);
        float p = q0 * bf2f(ku.x) + q1 * bf2f(ku.y) + q2 * bf2f(ku.z) + q3 * bf2f(ku.w);
        #pragma unroll
        for (int o = 32; o; o >>= 1) p += __shfl_xor(p, o);
        p *= 0.0625f;
        if (p > m) {
            float rr = __expf(m - p);
            den *= rr;
            acc.x *= rr; acc.y *= rr; acc.z *= rr; acc.w *= rr;
            m = p;
        }
        float ex = __expf(p - m);
        den += ex;
        acc.x += ex * bf2f(vu.x); acc.y += ex * bf2f(vu.y);
        acc.z += ex * bf2f(vu.z); acc.w += ex * bf2f(vu.w);
    }
    float rinv = 1.0f / fmaxf(den, 1e-16f);
    float4* o4 = (float4*)(out + (size_t)node * 256);
    float4 o = o4[lane];
    o.x += acc.x * rinv; o.y += acc.y * rinv; o.z += acc.z * rinv; o.w += acc.w * rinv;
    o4[lane] = o;
}

// ---------------- batch norm + leaky relu ----------------
__global__ __launch_bounds__(256) void k_bnstats(const float* __restrict__ out, float* __restrict__ sums,
                                                 float* __restrict__ sumsq) {
    int c = threadIdx.x;
    int rows_per = (NNODES + gridDim.x - 1) / gridDim.x;
    int r0 = blockIdx.x * rows_per;
    int r1 = r0 + rows_per; if (r1 > NNODES) r1 = NNODES;
    float s = 0.f, ss = 0.f;
    for (int r = r0; r < r1; r++) {
        float v = out[(size_t)r * 256 + c];
        s += v; ss += v * v;
    }
    atomicAdd(&sums[c], s);
    atomicAdd(&sumsq[c], ss);
}

__global__ __launch_bounds__(256) void k_bnapply(float4* __restrict__ out, const float* __restrict__ sums,
                                                 const float* __restrict__ sumsq, const float* __restrict__ gamma,
                                                 const float* __restrict__ beta) {
    int i = blockIdx.x * 256 + threadIdx.x;
    if (i >= NNODES * 64) return;
    int c4 = i & 63;
    float4 sc, sh;
    #pragma unroll
    for (int t = 0; t < 4; t++) {
        int c = c4 * 4 + t;
        float mu = sums[c] * (1.0f / NNODES);
        float var = sumsq[c] * (1.0f / NNODES) - mu * mu;
        float s = gamma[c] * rsqrtf(fmaxf(var, 0.f) + EPSBN);
        ((float*)&sc)[t] = s;
        ((float*)&sh)[t] = beta[c] - mu * s;
    }
    float4 v = out[i];
    v.x = v.x * sc.x + sh.x; v.y = v.y * sc.y + sh.y;
    v.z = v.z * sc.z + sh.z; v.w = v.w * sc.w + sh.w;
    v.x = v.x > 0.f ? v.x : 0.01f * v.x;
    v.y = v.y > 0.f ? v.y : 0.01f * v.y;
    v.z = v.z > 0.f ? v.z : 0.01f * v.z;
    v.w = v.w > 0.f ? v.w : 0.01f * v.w;
    out[i] = v;
}

extern "C" void kernel_launch(void* const* d_in, const int* in_sizes, int n_in,
                              void* d_out, int out_size, void* d_ws, size_t ws_size,
                              hipStream_t stream) {
    const float* x = (const float*)d_in[0];
    const int* ei = (const int*)d_in[1];
    const int* etype = (const int*)d_in[2];
    const float* Wrel = (const float*)d_in[3];
    const float* Wroot = (const float*)d_in[4];
    const float* b1 = (const float*)d_in[5];
    const float* Wq = (const float*)d_in[6];
    const float* bq = (const float*)d_in[7];
    const float* Wk = (const float*)d_in[8];
    const float* bk = (const float*)d_in[9];
    const float* Wv = (const float*)d_in[10];
    const float* bv = (const float*)d_in[11];
    const float* Ws = (const float*)d_in[12];
    const float* bs = (const float*)d_in[13];
    const float* gamma = (const float*)d_in[14];
    const float* beta = (const float*)d_in[15];
    float* out = (float*)d_out;

    const int* srcA = ei;
    const int* dstA = ei + NEDGES;

    char* w = (char*)d_ws;
    unsigned short* Yall = (unsigned short*)w;  w += (size_t)NNODES * 2048 * 2;
    unsigned short* x_bf = (unsigned short*)w;  w += (size_t)NNODES * 256 * 2;
    unsigned short* x1bf = (unsigned short*)w;  w += (size_t)NNODES * 256 * 2;
    float* xroot = (float*)w;                   w += (size_t)NNODES * 256 * 4;
    unsigned short* QKVbf = (unsigned short*)w; w += (size_t)NNODES * 768 * 2;
    unsigned short* BrelRoot = (unsigned short*)w; w += (size_t)2304 * 256 * 2;
    unsigned short* B2t = (unsigned short*)w;   w += (size_t)1024 * 256 * 2;
    float* bias2 = (float*)w;                   w += 1024 * 4;
    int* cnt = (int*)w;                         w += (size_t)NNODES * RREL * 4;
    float* invc = (float*)w;                    w += (size_t)NNODES * RREL * 4;
    int* deg = (int*)w;                         w += (size_t)NNODES * 4;
    int* startv = (int*)w;                      w += (size_t)NNODES * 4;
    int* cursor = (int*)w;                      w += (size_t)NNODES * 4;
    int* csr = (int*)w;                         w += (size_t)NEDGES * 4;
    float* sums = (float*)w;                    w += 1024;
    float* sumsq = (float*)w;                   w += 1024;
    size_t need = (size_t)(w - (char*)d_ws);
    if (ws_size < need) return;

    hipMemsetAsync(cnt, 0, (size_t)NNODES * RREL * 4, stream);
    hipMemsetAsync(sums, 0, 2048, stream);

    k_count<<<(NEDGES + 255) / 256, 256, 0, stream>>>(dstA, etype, cnt);
    k_invdeg<<<(NNODES + 255) / 256, 256, 0, stream>>>(cnt, invc, deg);
    k_scan<<<1, 256, 0, stream>>>(deg, startv, cursor);
    k_fill<<<(NEDGES + 255) / 256, 256, 0, stream>>>(srcA, dstA, etype, cursor, csr);

    k_prep<<<(PR0 + PR1 + PR2 + PR3) / 256, 256, 0, stream>>>(x, Wrel, Wroot, Wq, Wk, Wv, Ws,
                                                              bq, bk, bv, bs, x_bf, BrelRoot, B2t, bias2);

    // [Yall | xroot+b1] = x_bf @ [W_0..W_7|W_root]; 157 rowT x 18 colT, XCD-swizzled
    {
        int nwg = 157 * 18;           // 2826
        int q = nwg / 8, rr = nwg % 8;
        k_gemm5<4><<<nwg, 256, 0, stream>>>(x_bf, BrelRoot, b1, Yall, xroot, NNODES, 18, q, rr);
    }

    // x1bf = bf16(xroot + sum_r inv * Yall[src, r])
    k_rgcn<<<(NNODES + 3) / 4, 256, 0, stream>>>(Yall, csr, startv, deg, invc, xroot, x1bf);

    // [q|k|v -> QKVbf, skip -> out] = x1 @ [Wq|Wk|Wv|Wskip] + bias2; 157 x 8, swizzled
    {
        int nwg = 157 * 8;            // 1256
        int q = nwg / 8, rr = nwg % 8;
        k_gemm5<3><<<nwg, 256, 0, stream>>>(x1bf, B2t, bias2, QKVbf, out, NNODES, 8, q, rr);
    }

    k_attn<<<(NNODES + 3) / 4, 256, 0, stream>>>(QKVbf, csr, startv, deg, out);

    k_bnstats<<<400, 256, 0, stream>>>(out, sums, sumsq);
    k_bnapply<<<(NNODES * 64 + 255) / 256, 256, 0, stream>>>((float4*)out, sums, sumsq, gamma, beta);
}